// Round 2
// 266.848 us; speedup vs baseline: 1.0004x; 1.0004x over previous
//
#include <hip/hip_runtime.h>

#define B_ 8
#define H_ 8
#define S_ 4096
#define D_ 64
#define DM_ 768
#define NSTORE 4094            // S-2
#define DENOM 32752.0f         // B*(S-2)

typedef short bfrag_t __attribute__((ext_vector_type(8)));   // 8 bf16 (A/B frag)
typedef float f32x4_t __attribute__((ext_vector_type(4)));   // C/D frag

__device__ inline unsigned short f2bf(float x) {
    unsigned int u = __float_as_uint(x);
    unsigned int r = (u + 0x7fffu + ((u >> 16) & 1u)) >> 16;  // RNE
    return (unsigned short)r;
}

// pack 2 f32 -> 2 bf16 in one u32 (RNE), gfx950 V_CVT_PK_BF16_F32
__device__ inline unsigned int cvtpk(float lo, float hi) {
    unsigned int r;
    asm("v_cvt_pk_bf16_f32 %0, %1, %2" : "=v"(r) : "v"(lo), "v"(hi));
    return r;
}

// gfx950 lane-swap primitives: swap odd 16-rows of a with even 16-rows of b /
// hi-32 of a with lo-32 of b. Together: 4 instrs = 4x4 transpose across quads.
__device__ inline void pl16swap(float& a, float& b) {
    asm("v_permlane16_swap_b32 %0, %1" : "+v"(a), "+v"(b));
}
__device__ inline void pl32swap(float& a, float& b) {
    asm("v_permlane32_swap_b32 %0, %1" : "+v"(a), "+v"(b));
}

// VALU (DPP) butterfly add within 16-lane row group
template <int CTRL>
__device__ inline float dpp_add(float x) {
    int y = __builtin_amdgcn_update_dpp(0, __float_as_int(x), CTRL, 0xf, 0xf, true);
    return x + __int_as_float(y);
}

__device__ inline void async_copy16(const void* g, void* lds) {
    __builtin_amdgcn_global_load_lds((__attribute__((address_space(1))) void*)g,
                                     (__attribute__((address_space(3))) void*)lds,
                                     16, 0, 0);
}

#define MFMA16(a, b, c) __builtin_amdgcn_mfma_f32_16x16x32_bf16((a), (b), (c), 0, 0, 0)

// ---------------------------------------------------------------------------
// Kernel 1: per-head G = Qh^T Qh, U = Qh^T Vh (64x64, K = rows) where
// Qh = Q/||Q||, Vh = V*||Q|| (norm folded symmetrically -> only 2 LDS arrays,
// shared A-fragment). Staging: float4 load -> DPP norm reduce -> permlane
// 4x4 quad transpose -> cvt_pk -> single ds_write_b64 per array into
// XOR-swizzled [p][s] layout (granule g stored at g ^ (p&15), 8B granules;
// bank-balanced for writes and b64 frag reads). Double-buffered LDS, one
// barrier per 64-row tile, register prefetch of next tile.
// PART: partial slabs; else atomics. Also emits bf16 Q copy (Qbf).
// ---------------------------------------------------------------------------
template <bool PART>
__global__ __launch_bounds__(256, 4) void gram_kernel(
    const float* __restrict__ Q, const float* __restrict__ V,
    float* __restrict__ gG, float* __restrict__ gU,
    unsigned short* __restrict__ Qbf, float* __restrict__ gP, int writeQbf) {
    const int split = blockIdx.x, h = blockIdx.y, b = blockIdx.z;
    const int nsplit = gridDim.x;
    const int rowsPer = 4096 / nsplit;
    const int nTiles = rowsPer >> 6;
    const int t = threadIdx.x;
    const int wave = t >> 6, lane = t & 63;
    const int quad = lane >> 4, l15 = lane & 15;
    const int rgrp = t >> 4;           // row group in tile: wave*4 + quad
    const int c4 = t & 15;             // 4-col chunk
    __shared__ __align__(16) unsigned short Qs[2][4096];
    __shared__ __align__(16) unsigned short Vs[2][4096];

    const size_t bh = (size_t)(b * H_ + h);
    const float* Qbh = Q + bh * S_ * D_;
    const float* Vbh = V + bh * S_ * D_;
    unsigned short* Qo = Qbf + bh * S_ * D_;

    f32x4_t accG[4] = {}, accU[4] = {};
    const int r0 = split * rowsPer;

    float4 qr[4], vr[4];
    auto loadT = [&](int tile) {
        const int rbase = r0 + tile * 64;
        #pragma unroll
        for (int i = 0; i < 4; ++i) {
            int r = rbase + i * 16 + rgrp;
            qr[i] = *(const float4*)(Qbh + (size_t)r * D_ + c4 * 4);
            vr[i] = (r < NSTORE) ? *(const float4*)(Vbh + (size_t)(r + 2) * D_ + c4 * 4)
                                 : make_float4(0.f, 0.f, 0.f, 0.f);
        }
    };
    // read 8 ascending-s bf16 at column p from swizzled layout (2x b64)
    auto rd8 = [&](const unsigned short* arr, int p, int gk) {
        const int bx = p & 15;
        uint2 lo = *(const uint2*)&arr[p * 64 + (((gk * 2) ^ bx) << 2)];
        uint2 hi = *(const uint2*)&arr[p * 64 + (((gk * 2 + 1) ^ bx) << 2)];
        union { uint2 u2[2]; bfrag_t f; } u;
        u.u2[0] = lo; u.u2[1] = hi;
        return u.f;
    };

    loadT(0);
    for (int tile = 0; tile < nTiles; ++tile) {
        const int buf = tile & 1;
        const int rbase = r0 + tile * 64;
        unsigned short* Qb_ = Qs[buf];
        unsigned short* Vb_ = Vs[buf];
        #pragma unroll
        for (int i = 0; i < 4; ++i) {
            int r = rbase + i * 16 + rgrp;
            float4 q4 = qr[i], v4 = vr[i];
            if (writeQbf) {   // full, unscaled Q (all rows incl. >= NSTORE)
                uint2 u = make_uint2(cvtpk(q4.x, q4.y), cvtpk(q4.z, q4.w));
                *(uint2*)(Qo + (size_t)r * D_ + c4 * 4) = u;
            }
            if (r >= NSTORE) q4 = make_float4(0.f, 0.f, 0.f, 0.f);
            float ss = q4.x * q4.x + q4.y * q4.y + q4.z * q4.z + q4.w * q4.w;
            ss = dpp_add<0xB1>(ss);    // quad_perm xor1
            ss = dpp_add<0x4E>(ss);    // quad_perm xor2
            ss = dpp_add<0x141>(ss);   // row_half_mirror
            ss = dpp_add<0x140>(ss);   // row_mirror -> sum over 16 lanes
            float sc = fmaxf(ss, 1e-16f);     // clip(norm,eps)^2
            float sr = rsqrtf(sc);            // 1/norm
            float sv = sc * sr;               // norm
            float a0 = q4.x * sr, a1 = q4.y * sr, a2 = q4.z * sr, a3 = q4.w * sr;
            float b0 = v4.x * sv, b1 = v4.y * sv, b2 = v4.z * sv, b3 = v4.w * sv;
            // 4x4 transpose across quads: after, reg j = (row rbase-local sb+j,
            // col p = c4*4 + quad), sb = i*16 + wave*4
            pl16swap(a0, a1); pl16swap(a2, a3);
            pl32swap(a0, a2); pl32swap(a1, a3);
            pl16swap(b0, b1); pl16swap(b2, b3);
            pl32swap(b0, b2); pl32swap(b1, b3);
            const int p = c4 * 4 + quad;
            const int off = p * 64 + (((i * 4 + wave) ^ (p & 15)) << 2);
            *(uint2*)&Qb_[off] = make_uint2(cvtpk(a0, a1), cvtpk(a2, a3));
            *(uint2*)&Vb_[off] = make_uint2(cvtpk(b0, b1), cvtpk(b2, b3));
        }
        if (tile + 1 < nTiles) loadT(tile + 1);   // prefetch hides under MFMA
        __syncthreads();                           // single barrier per tile
        #pragma unroll
        for (int c = 0; c < 2; ++c) {
            const int gk = c * 4 + quad;           // k-granule of 8
            bfrag_t af = rd8(Qb_, wave * 16 + l15, gk);
            #pragma unroll
            for (int j = 0; j < 4; ++j) {
                bfrag_t bq = rd8(Qb_, j * 16 + l15, gk);
                bfrag_t bv = rd8(Vb_, j * 16 + l15, gk);
                accG[j] = MFMA16(af, bq, accG[j]);
                accU[j] = MFMA16(af, bv, accU[j]);
            }
        }
        // no second barrier: next write goes to the other buffer; this buffer
        // is only rewritten after the next tile's barrier.
    }
    // C layout: col = j*16+l15, row = wave*16 + quad*4 + r
    if (PART) {
        const int slab = split * 8 + b;                  // 0..127
        float* base = gP + ((size_t)(h * 128 + slab) * 2) * 4096;
        #pragma unroll
        for (int j = 0; j < 4; ++j) {
            int coln = j * 16 + l15;
            #pragma unroll
            for (int r = 0; r < 4; ++r) {
                int row = wave * 16 + quad * 4 + r;
                base[row * 64 + coln]        = accG[j][r];
                base[4096 + row * 64 + coln] = accU[j][r];
            }
        }
    } else {
        float* gGh = gG + h * 4096;
        float* gUh = gU + h * 4096;
        #pragma unroll
        for (int j = 0; j < 4; ++j) {
            int coln = j * 16 + l15;
            #pragma unroll
            for (int r = 0; r < 4; ++r) {
                int row = wave * 16 + quad * 4 + r;
                atomicAdd(&gGh[row * 64 + coln], accG[j][r]);
                atomicAdd(&gUh[row * 64 + coln], accU[j][r]);
            }
        }
    }
}

// ---------------------------------------------------------------------------
// Kernel 1b: sum 128 partial slabs -> gG/gU. grid (8 h, 32 chunks), block 256.
// ---------------------------------------------------------------------------
__global__ __launch_bounds__(256) void reduce_kernel(
    const float* __restrict__ gP, float* __restrict__ gG, float* __restrict__ gU) {
    const int h = blockIdx.x, chunk = blockIdx.y, t = threadIdx.x;
    const int arr = t >> 7, idx = chunk * 128 + (t & 127);
    const float* base = gP + ((size_t)(h * 128) * 2 + arr) * 4096 + idx;
    float s = 0.f;
    #pragma unroll 8
    for (int sl = 0; sl < 128; ++sl) s += base[(size_t)sl * 2 * 4096];
    (arr ? gU : gG)[h * 4096 + idx] = s;
}

// ---------------------------------------------------------------------------
// Kernel 2: T_new[h] = 0.99*(trace - G@trace/denom) + 0.1*U/denom. grid=8.
// float4 microtile: thread owns (p, 16 q).
// ---------------------------------------------------------------------------
__global__ __launch_bounds__(256) void trace_kernel(
    const float* __restrict__ gG, const float* __restrict__ gU,
    const float* __restrict__ trace, float* __restrict__ Tnew) {
    const int h = blockIdx.x, t = threadIdx.x;
    __shared__ float Gs[64][68];
    __shared__ float Ts[64][68];
    const float* Gh = gG + h * 4096;
    const float* Uh = gU + h * 4096;
    const float* Th = trace + h * 4096;
    float* To = Tnew + h * 4096;
    for (int k = 0; k < 16; ++k) {
        int e = k * 256 + t;
        Gs[e >> 6][e & 63] = Gh[e];
        Ts[e >> 6][e & 63] = Th[e];
    }
    __syncthreads();
    const int p = t >> 2, q0 = (t & 3) * 16;
    f32x4_t acc[4] = {};
    for (int r = 0; r < 64; ++r) {
        float g = Gs[p][r];
        #pragma unroll
        for (int i = 0; i < 4; ++i) {
            f32x4_t tv = *(const f32x4_t*)&Ts[r][q0 + i * 4];
            acc[i] += g * tv;
        }
    }
    const float inv = 1.0f / DENOM;
    #pragma unroll
    for (int i = 0; i < 4; ++i) {
        int e = p * 64 + q0 + i * 4;
        f32x4_t ts = *(const f32x4_t*)&Ts[p][q0 + i * 4];
        f32x4_t uu = *(const f32x4_t*)(Uh + e);
        f32x4_t res = 0.99f * (ts - acc[i] * inv) + (0.1f * inv) * uu;
        *(f32x4_t*)(To + e) = res;
    }
}

// ---------------------------------------------------------------------------
// Kernel 3: WcT[n][h*64+p] = sum_q T_new[h][p][q] * W_out[n][h*64+q], bf16.
// grid (6 nc, 8 h). One barrier; thread computes 8n x 4p tile via float4.
// ---------------------------------------------------------------------------
__global__ __launch_bounds__(256) void wc_kernel(
    const float* __restrict__ Tnew, const float* __restrict__ Wout,
    unsigned short* __restrict__ WcT) {
    const int nc = blockIdx.x, h = blockIdx.y, t = threadIdx.x;
    __shared__ float TsT[64][68];    // [q][p]
    __shared__ float WbT[64][132];   // [q][n]
    const float* Th = Tnew + h * 4096;
    #pragma unroll
    for (int i = 0; i < 4; ++i) {
        int f = i * 256 + t;
        int p = f >> 4, q4 = f & 15;
        float4 v = *(const float4*)(Th + p * 64 + q4 * 4);
        TsT[q4 * 4 + 0][p] = v.x; TsT[q4 * 4 + 1][p] = v.y;
        TsT[q4 * 4 + 2][p] = v.z; TsT[q4 * 4 + 3][p] = v.w;
    }
    #pragma unroll
    for (int i = 0; i < 8; ++i) {
        int f = i * 256 + t;
        int n = f >> 4, q4 = f & 15;
        float4 w = *(const float4*)(Wout + (size_t)(nc * 128 + n) * 512 + h * 64 + q4 * 4);
        WbT[q4 * 4 + 0][n] = w.x; WbT[q4 * 4 + 1][n] = w.y;
        WbT[q4 * 4 + 2][n] = w.z; WbT[q4 * 4 + 3][n] = w.w;
    }
    __syncthreads();
    const int n0 = (t >> 4) * 8, p0 = (t & 15) * 4;
    f32x4_t acc[8] = {};
    for (int q = 0; q < 64; ++q) {
        f32x4_t tp = *(const f32x4_t*)&TsT[q][p0];
        f32x4_t w0 = *(const f32x4_t*)&WbT[q][n0];
        f32x4_t w1 = *(const f32x4_t*)&WbT[q][n0 + 4];
        #pragma unroll
        for (int i = 0; i < 4; ++i) acc[i] += w0[i] * tp;
        #pragma unroll
        for (int i = 0; i < 4; ++i) acc[4 + i] += w1[i] * tp;
    }
    #pragma unroll
    for (int i = 0; i < 8; ++i) {
        int n = nc * 128 + n0 + i;
        ushort4 u;
        u.x = f2bf(acc[i][0]); u.y = f2bf(acc[i][1]);
        u.z = f2bf(acc[i][2]); u.w = f2bf(acc[i][3]);
        *(ushort4*)(WcT + (size_t)n * 512 + h * 64 + p0) = u;
    }
}

// ---------------------------------------------------------------------------
// Kernel 4: out(32768x768) = Q_addr(32768x512) @ Wc(512x768), bf16 MFMA.
// 128x128 tile, BK=64, global_load_lds width=16 into swizzled [128][64]
// (granule g stored at g ^ (row&7) -> conflict-free b128 frag reads).
// ---------------------------------------------------------------------------
__global__ __launch_bounds__(256, 3) void matmul_fast(
    const unsigned short* __restrict__ Qb, const unsigned short* __restrict__ WcT,
    float* __restrict__ out) {
    const int mTile = blockIdx.x;  // 0..255
    const int nTile = blockIdx.y;  // 0..5
    const int t = threadIdx.x;
    const int wave = t >> 6, lane = t & 63;
    const int wm = wave >> 1, wn = wave & 1;
    const int quad = lane >> 4, l15 = lane & 15;
    __shared__ __align__(16) unsigned short As[128 * 64];
    __shared__ __align__(16) unsigned short Bs[128 * 64];
    const int b = mTile >> 5;
    const int s0 = (mTile & 31) * 128;
    const int nBase = nTile * 128;
    const int rl8 = lane >> 3, g = lane & 7;
    const int gs = g ^ rl8;                    // swizzled source granule
    f32x4_t acc[4][4] = {};

    for (int h = 0; h < 8; ++h) {
        const unsigned short* Qbh = Qb + (size_t)(b * H_ + h) * S_ * D_;
        #pragma unroll
        for (int k = 0; k < 4; ++k) {
            int ch = wave * 4 + k;             // chunk 0..15 (8 rows each)
            int row = ch * 8 + rl8;
            int s = s0 + row;
            int sc = (s > 0) ? (s - 1) : 0;
            async_copy16(Qbh + (size_t)sc * 64 + gs * 8, &As[ch * 512 + lane * 8]);
            async_copy16(WcT + (size_t)(nBase + row) * 512 + h * 64 + gs * 8,
                         &Bs[ch * 512 + lane * 8]);
        }
        __syncthreads();
        if (s0 == 0) {                          // block-uniform: zero A row 0 (s-1 = -1)
            if (t < 8) ((uint4*)As)[t] = make_uint4(0, 0, 0, 0);
            __syncthreads();
        }
        #pragma unroll
        for (int c = 0; c < 2; ++c) {
            int gk = c * 4 + quad;
            bfrag_t af[4], bf[4];
            #pragma unroll
            for (int i = 0; i < 4; ++i) {
                int row = wm * 64 + i * 16 + l15;
                af[i] = *(const bfrag_t*)&As[row * 64 + ((gk ^ (row & 7)) << 3)];
            }
            #pragma unroll
            for (int j = 0; j < 4; ++j) {
                int row = wn * 64 + j * 16 + l15;
                bf[j] = *(const bfrag_t*)&Bs[row * 64 + ((gk ^ (row & 7)) << 3)];
            }
            #pragma unroll
            for (int i = 0; i < 4; ++i)
                #pragma unroll
                for (int j = 0; j < 4; ++j)
                    acc[i][j] = MFMA16(af[i], bf[j], acc[i][j]);
        }
        __syncthreads();
    }
    const size_t mBase = (size_t)mTile * 128;
    #pragma unroll
    for (int i = 0; i < 4; ++i) {
        int mrow = wm * 64 + i * 16 + quad * 4;
        #pragma unroll
        for (int j = 0; j < 4; ++j) {
            int n = nBase + wn * 64 + j * 16 + l15;
            #pragma unroll
            for (int r = 0; r < 4; ++r)
                out[(mBase + mrow + r) * DM_ + n] = acc[i][j][r];
        }
    }
}

// Fallback GEMM reading fp32 Q (used only if ws can't hold Qbf).
__global__ __launch_bounds__(256, 2) void matmul_f32(
    const float* __restrict__ Qf, const unsigned short* __restrict__ WcT,
    float* __restrict__ out) {
    const int mTile = blockIdx.x, nTile = blockIdx.y;
    const int t = threadIdx.x;
    const int wave = t >> 6, lane = t & 63;
    const int wm = wave >> 1, wn = wave & 1;
    const int quad = lane >> 4, l15 = lane & 15;
    __shared__ __align__(16) unsigned short As[128][72];
    __shared__ __align__(16) unsigned short Bs[128][72];
    const int b = mTile >> 5;
    const int s0 = (mTile & 31) * 128;
    const int nBase = nTile * 128;
    f32x4_t acc[4][4] = {};
    for (int h = 0; h < 8; ++h) {
        const float* Qbh = Qf + (size_t)(b * H_ + h) * S_ * D_;
        #pragma unroll
        for (int i = 0; i < 8; ++i) {
            int f = i * 256 + t;
            int row = f >> 4, c4 = f & 15;
            int s = s0 + row;
            float4 q4 = make_float4(0.f, 0.f, 0.f, 0.f);
            if (s > 0) q4 = *(const float4*)(Qbh + (size_t)(s - 1) * D_ + c4 * 4);
            ushort4 u;
            u.x = f2bf(q4.x); u.y = f2bf(q4.y); u.z = f2bf(q4.z); u.w = f2bf(q4.w);
            *(ushort4*)(&As[row][c4 * 4]) = u;
        }
        #pragma unroll
        for (int i = 0; i < 4; ++i) {
            int f = i * 256 + t;
            int row = f >> 3, c8 = f & 7;
            uint4 w = *(const uint4*)(WcT + (size_t)(nBase + row) * 512 + h * 64 + c8 * 8);
            *(uint4*)(&Bs[row][c8 * 8]) = w;
        }
        __syncthreads();
        #pragma unroll
        for (int c = 0; c < 2; ++c) {
            int k0 = c * 32 + quad * 8;
            bfrag_t af[4], bf[4];
            #pragma unroll
            for (int i = 0; i < 4; ++i)
                af[i] = *(const bfrag_t*)(&As[wm * 64 + i * 16 + l15][k0]);
            #pragma unroll
            for (int j = 0; j < 4; ++j)
                bf[j] = *(const bfrag_t*)(&Bs[wn * 64 + j * 16 + l15][k0]);
            #pragma unroll
            for (int i = 0; i < 4; ++i)
                #pragma unroll
                for (int j = 0; j < 4; ++j)
                    acc[i][j] = MFMA16(af[i], bf[j], acc[i][j]);
        }
        __syncthreads();
    }
    const size_t mBase = (size_t)mTile * 128;
    #pragma unroll
    for (int i = 0; i < 4; ++i) {
        int mrow = wm * 64 + i * 16 + quad * 4;
        #pragma unroll
        for (int j = 0; j < 4; ++j) {
            int n = nBase + wn * 64 + j * 16 + l15;
            #pragma unroll
            for (int r = 0; r < 4; ++r)
                out[(mBase + mrow + r) * DM_ + n] = acc[i][j][r];
        }
    }
}

// ---------------------------------------------------------------------------
extern "C" void kernel_launch(void* const* d_in, const int* in_sizes, int n_in,
                              void* d_out, int out_size, void* d_ws, size_t ws_size,
                              hipStream_t stream) {
    const float* Q     = (const float*)d_in[0];
    const float* V     = (const float*)d_in[1];
    const float* trace = (const float*)d_in[2];
    const float* Wout  = (const float*)d_in[3];
    float* out = (float*)d_out;

    // ws layout
    float* gG   = (float*)d_ws;                                      // @0       128 KB
    float* gU   = gG + 32768;                                        // @128K    128 KB
    float* Tnew = gU + 32768;                                        // @256K    128 KB
    unsigned short* WcT = (unsigned short*)(Tnew + 32768);           // @384K    768 KB
    unsigned short* Qbf = WcT + 393216;                              // @1152K   32 MB
    float* gP = (float*)(Qbf + (size_t)B_ * H_ * S_ * D_);           // @33.1M   32 MB

    const size_t needQbf  = 1179648u + 33554432u;
    const size_t needFull = needQbf + 33554432u;
    const int mode = (ws_size >= needFull) ? 2 : ((ws_size >= needQbf) ? 1 : 0);

    if (mode == 2) {
        gram_kernel<true><<<dim3(16, 8, 8), 256, 0, stream>>>(Q, V, gG, gU, Qbf, gP, 1);
        reduce_kernel<<<dim3(8, 32), 256, 0, stream>>>(gP, gG, gU);
    } else {
        hipMemsetAsync(d_ws, 0, 2 * 32768 * sizeof(float), stream);
        gram_kernel<false><<<dim3(8, 8, 8), 256, 0, stream>>>(Q, V, gG, gU, Qbf, gP, mode >= 1);
    }
    trace_kernel<<<8, 256, 0, stream>>>(gG, gU, trace, Tnew);
    wc_kernel<<<dim3(6, 8), 256, 0, stream>>>(Tnew, Wout, WcT);
    if (mode >= 1)
        matmul_fast<<<dim3(256, 6), 256, 0, stream>>>(Qbf, WcT, out);
    else
        matmul_f32<<<dim3(256, 6), 256, 0, stream>>>(Q, WcT, out);
}

// Round 3
// 262.003 us; speedup vs baseline: 1.0189x; 1.0185x over previous
//
#include <hip/hip_runtime.h>

#define B_ 8
#define H_ 8
#define S_ 4096
#define D_ 64
#define DM_ 768
#define NSTORE 4094            // S-2
#define DENOM 32752.0f         // B*(S-2)

typedef short bfrag_t __attribute__((ext_vector_type(8)));   // 8 bf16 (A/B frag)
typedef float f32x4_t __attribute__((ext_vector_type(4)));   // C/D frag

__device__ inline unsigned short f2bf(float x) {
    unsigned int u = __float_as_uint(x);
    unsigned int r = (u + 0x7fffu + ((u >> 16) & 1u)) >> 16;  // RNE
    return (unsigned short)r;
}

// pack 2 f32 -> 2 bf16 in one u32 (RNE), gfx950 V_CVT_PK_BF16_F32
__device__ inline unsigned int cvtpk(float lo, float hi) {
    unsigned int r;
    asm("v_cvt_pk_bf16_f32 %0, %1, %2" : "=v"(r) : "v"(lo), "v"(hi));
    return r;
}

// gfx950 lane-swap primitives (4 instrs = 4x4 transpose across quads)
__device__ inline void pl16swap(float& a, float& b) {
    asm("v_permlane16_swap_b32 %0, %1" : "+v"(a), "+v"(b));
}
__device__ inline void pl32swap(float& a, float& b) {
    asm("v_permlane32_swap_b32 %0, %1" : "+v"(a), "+v"(b));
}

// VALU (DPP) butterfly add within 16-lane row group
template <int CTRL>
__device__ inline float dpp_add(float x) {
    int y = __builtin_amdgcn_update_dpp(0, __float_as_int(x), CTRL, 0xf, 0xf, true);
    return x + __int_as_float(y);
}

__device__ inline void async_copy16(const void* g, void* lds) {
    __builtin_amdgcn_global_load_lds((__attribute__((address_space(1))) void*)g,
                                     (__attribute__((address_space(3))) void*)lds,
                                     16, 0, 0);
}

// Raw workgroup barrier that does NOT drain vmcnt: LDS-write visibility only.
// (hipcc's __syncthreads inserts s_waitcnt vmcnt(0) which serializes the
// register-prefetch global loads into the barrier -> burst-wait convoy.)
__device__ inline void barrier_lds_only() {
    __builtin_amdgcn_sched_barrier(0);
    asm volatile("s_waitcnt lgkmcnt(0)" ::: "memory");
    __builtin_amdgcn_s_barrier();
    __builtin_amdgcn_sched_barrier(0);
}

#define MFMA16(a, b, c) __builtin_amdgcn_mfma_f32_16x16x32_bf16((a), (b), (c), 0, 0, 0)

// ---------------------------------------------------------------------------
// Kernel 1: per-head G = Qh^T Qh, U = Qh^T Vh (64x64, K = rows) where
// Qh = Q/||Q||, Vh = V*||Q||. Register prefetch of next tile's global loads
// stays OUTSTANDING across the (raw) barrier -> latency hides under MFMA.
// Staging: DPP norm reduce -> permlane 4x4 transpose -> cvt_pk ->
// ds_write_b64 into XOR-swizzled [p][s] bf16 layout. Double-buffered LDS,
// one raw barrier per tile. PART: partial slabs; else atomics.
// ---------------------------------------------------------------------------
template <bool PART>
__global__ __launch_bounds__(256, 4) void gram_kernel(
    const float* __restrict__ Q, const float* __restrict__ V,
    float* __restrict__ gG, float* __restrict__ gU,
    unsigned short* __restrict__ Qbf, float* __restrict__ gP, int writeQbf) {
    const int split = blockIdx.x, h = blockIdx.y, b = blockIdx.z;
    const int nsplit = gridDim.x;
    const int rowsPer = 4096 / nsplit;
    const int nTiles = rowsPer >> 6;
    const int t = threadIdx.x;
    const int wave = t >> 6, lane = t & 63;
    const int quad = lane >> 4, l15 = lane & 15;
    const int rgrp = t >> 4;           // row group in tile: wave*4 + quad
    const int c4 = t & 15;             // 4-col chunk
    __shared__ __align__(16) unsigned short Qs[2][4096];
    __shared__ __align__(16) unsigned short Vs[2][4096];

    const size_t bh = (size_t)(b * H_ + h);
    const float* Qbh = Q + bh * S_ * D_;
    const float* Vbh = V + bh * S_ * D_;
    unsigned short* Qo = Qbf + bh * S_ * D_;

    f32x4_t accG[4] = {}, accU[4] = {};
    const int r0 = split * rowsPer;

    float4 qr[4], vr[4];
    auto loadT = [&](int tile) {
        const int rbase = r0 + tile * 64;
        #pragma unroll
        for (int i = 0; i < 4; ++i) {
            int r = rbase + i * 16 + rgrp;
            qr[i] = *(const float4*)(Qbh + (size_t)r * D_ + c4 * 4);
            vr[i] = (r < NSTORE) ? *(const float4*)(Vbh + (size_t)(r + 2) * D_ + c4 * 4)
                                 : make_float4(0.f, 0.f, 0.f, 0.f);
        }
    };
    // read 8 ascending-s bf16 at column p from swizzled layout (2x b64)
    auto rd8 = [&](const unsigned short* arr, int p, int gk) {
        const int bx = p & 15;
        uint2 lo = *(const uint2*)&arr[p * 64 + (((gk * 2) ^ bx) << 2)];
        uint2 hi = *(const uint2*)&arr[p * 64 + (((gk * 2 + 1) ^ bx) << 2)];
        union { uint2 u2[2]; bfrag_t f; } u;
        u.u2[0] = lo; u.u2[1] = hi;
        return u.f;
    };

    loadT(0);
    for (int tile = 0; tile < nTiles; ++tile) {
        const int buf = tile & 1;
        const int rbase = r0 + tile * 64;
        unsigned short* Qb_ = Qs[buf];
        unsigned short* Vb_ = Vs[buf];
        #pragma unroll
        for (int i = 0; i < 4; ++i) {
            int r = rbase + i * 16 + rgrp;
            float4 q4 = qr[i], v4 = vr[i];
            if (writeQbf) {   // full, unscaled Q (all rows incl. >= NSTORE)
                uint2 u = make_uint2(cvtpk(q4.x, q4.y), cvtpk(q4.z, q4.w));
                *(uint2*)(Qo + (size_t)r * D_ + c4 * 4) = u;
            }
            if (r >= NSTORE) q4 = make_float4(0.f, 0.f, 0.f, 0.f);
            float ss = q4.x * q4.x + q4.y * q4.y + q4.z * q4.z + q4.w * q4.w;
            ss = dpp_add<0xB1>(ss);    // quad_perm xor1
            ss = dpp_add<0x4E>(ss);    // quad_perm xor2
            ss = dpp_add<0x141>(ss);   // row_half_mirror
            ss = dpp_add<0x140>(ss);   // row_mirror -> sum over 16 lanes
            float sc = fmaxf(ss, 1e-16f);     // clip(norm,eps)^2
            float sr = rsqrtf(sc);            // 1/norm
            float sv = sc * sr;               // norm
            float a0 = q4.x * sr, a1 = q4.y * sr, a2 = q4.z * sr, a3 = q4.w * sr;
            float b0 = v4.x * sv, b1 = v4.y * sv, b2 = v4.z * sv, b3 = v4.w * sv;
            pl16swap(a0, a1); pl16swap(a2, a3);
            pl32swap(a0, a2); pl32swap(a1, a3);
            pl16swap(b0, b1); pl16swap(b2, b3);
            pl32swap(b0, b2); pl32swap(b1, b3);
            const int p = c4 * 4 + quad;
            const int off = p * 64 + (((i * 4 + wave) ^ (p & 15)) << 2);
            *(uint2*)&Qb_[off] = make_uint2(cvtpk(a0, a1), cvtpk(a2, a3));
            *(uint2*)&Vb_[off] = make_uint2(cvtpk(b0, b1), cvtpk(b2, b3));
        }
        if (tile + 1 < nTiles) loadT(tile + 1);   // prefetch: stays in flight
        barrier_lds_only();                        // NO vmcnt drain
        #pragma unroll
        for (int c = 0; c < 2; ++c) {
            const int gk = c * 4 + quad;           // k-granule of 8
            bfrag_t af = rd8(Qb_, wave * 16 + l15, gk);
            #pragma unroll
            for (int j = 0; j < 4; ++j) {
                bfrag_t bq = rd8(Qb_, j * 16 + l15, gk);
                bfrag_t bv = rd8(Vb_, j * 16 + l15, gk);
                accG[j] = MFMA16(af, bq, accG[j]);
                accU[j] = MFMA16(af, bv, accU[j]);
            }
        }
        // dbuf: next staging writes the other buffer; a wave only reaches the
        // next barrier after its reads here were consumed by MFMA.
    }
    // C layout: col = j*16+l15, row = wave*16 + quad*4 + r
    if (PART) {
        const int slab = split * 8 + b;                  // 0..127
        float* base = gP + ((size_t)(h * 128 + slab) * 2) * 4096;
        #pragma unroll
        for (int j = 0; j < 4; ++j) {
            int coln = j * 16 + l15;
            #pragma unroll
            for (int r = 0; r < 4; ++r) {
                int row = wave * 16 + quad * 4 + r;
                base[row * 64 + coln]        = accG[j][r];
                base[4096 + row * 64 + coln] = accU[j][r];
            }
        }
    } else {
        float* gGh = gG + h * 4096;
        float* gUh = gU + h * 4096;
        #pragma unroll
        for (int j = 0; j < 4; ++j) {
            int coln = j * 16 + l15;
            #pragma unroll
            for (int r = 0; r < 4; ++r) {
                int row = wave * 16 + quad * 4 + r;
                atomicAdd(&gGh[row * 64 + coln], accG[j][r]);
                atomicAdd(&gUh[row * 64 + coln], accU[j][r]);
            }
        }
    }
}

// ---------------------------------------------------------------------------
// Kernel 1b: sum 128 partial slabs -> gG/gU. grid (8 h, 32 chunks), block 256.
// ---------------------------------------------------------------------------
__global__ __launch_bounds__(256) void reduce_kernel(
    const float* __restrict__ gP, float* __restrict__ gG, float* __restrict__ gU) {
    const int h = blockIdx.x, chunk = blockIdx.y, t = threadIdx.x;
    const int arr = t >> 7, idx = chunk * 128 + (t & 127);
    const float* base = gP + ((size_t)(h * 128) * 2 + arr) * 4096 + idx;
    float s = 0.f;
    #pragma unroll 8
    for (int sl = 0; sl < 128; ++sl) s += base[(size_t)sl * 2 * 4096];
    (arr ? gU : gG)[h * 4096 + idx] = s;
}

// ---------------------------------------------------------------------------
// Kernel 3 (fused trace+wc): per (nc,h) block recomputes
// T = 0.99*(trace - G@trace/denom) + 0.1*U/denom (64x64, 262K FMA — cheap),
// then WcT[n][h*64+p] = sum_q T[p][q] * W_out[n][h*64+q], bf16 out.
// Removes trace_kernel launch + Tnew round-trip.
// ---------------------------------------------------------------------------
__global__ __launch_bounds__(256) void wc_kernel(
    const float* __restrict__ gG, const float* __restrict__ gU,
    const float* __restrict__ trace, const float* __restrict__ Wout,
    unsigned short* __restrict__ WcT) {
    const int nc = blockIdx.x, h = blockIdx.y, t = threadIdx.x;
    __shared__ float Gs[64][68];
    __shared__ float Ts[64][68];
    __shared__ float TsT[64][68];    // [q][p]
    __shared__ float WbT[64][132];   // [q][n]
    const float* Gh = gG + h * 4096;
    const float* Uh = gU + h * 4096;
    const float* Th = trace + h * 4096;
    #pragma unroll
    for (int k = 0; k < 16; ++k) {
        int e = k * 256 + t;
        Gs[e >> 6][e & 63] = Gh[e];
        Ts[e >> 6][e & 63] = Th[e];
    }
    #pragma unroll
    for (int i = 0; i < 8; ++i) {
        int f = i * 256 + t;
        int n = f >> 4, q4 = f & 15;
        float4 w = *(const float4*)(Wout + (size_t)(nc * 128 + n) * 512 + h * 64 + q4 * 4);
        WbT[q4 * 4 + 0][n] = w.x; WbT[q4 * 4 + 1][n] = w.y;
        WbT[q4 * 4 + 2][n] = w.z; WbT[q4 * 4 + 3][n] = w.w;
    }
    __syncthreads();
    // ---- T compute (was trace_kernel): thread owns (p, 16 q) ----
    {
        const int p = t >> 2, q0 = (t & 3) * 16;
        f32x4_t acc[4] = {};
        for (int r = 0; r < 64; ++r) {
            float g = Gs[p][r];
            #pragma unroll
            for (int i = 0; i < 4; ++i) {
                f32x4_t tv = *(const f32x4_t*)&Ts[r][q0 + i * 4];
                acc[i] += g * tv;
            }
        }
        const float inv = 1.0f / DENOM;
        #pragma unroll
        for (int i = 0; i < 4; ++i) {
            f32x4_t ts = *(const f32x4_t*)&Ts[p][q0 + i * 4];
            f32x4_t uu = *(const f32x4_t*)(Uh + p * 64 + q0 + i * 4);
            f32x4_t res = 0.99f * (ts - acc[i] * inv) + (0.1f * inv) * uu;
            TsT[q0 + i * 4 + 0][p] = res[0];
            TsT[q0 + i * 4 + 1][p] = res[1];
            TsT[q0 + i * 4 + 2][p] = res[2];
            TsT[q0 + i * 4 + 3][p] = res[3];
        }
    }
    __syncthreads();
    // ---- Wc chunk: thread computes 8n x 4p tile ----
    const int n0 = (t >> 4) * 8, p0 = (t & 15) * 4;
    f32x4_t acc[8] = {};
    for (int q = 0; q < 64; ++q) {
        f32x4_t tp = *(const f32x4_t*)&TsT[q][p0];
        f32x4_t w0 = *(const f32x4_t*)&WbT[q][n0];
        f32x4_t w1 = *(const f32x4_t*)&WbT[q][n0 + 4];
        #pragma unroll
        for (int i = 0; i < 4; ++i) acc[i] += w0[i] * tp;
        #pragma unroll
        for (int i = 0; i < 4; ++i) acc[4 + i] += w1[i] * tp;
    }
    #pragma unroll
    for (int i = 0; i < 8; ++i) {
        int n = nc * 128 + n0 + i;
        ushort4 u;
        u.x = f2bf(acc[i][0]); u.y = f2bf(acc[i][1]);
        u.z = f2bf(acc[i][2]); u.w = f2bf(acc[i][3]);
        *(ushort4*)(WcT + (size_t)n * 512 + h * 64 + p0) = u;
    }
}

// ---------------------------------------------------------------------------
// Kernel 4: out(32768x768) = Q_addr(32768x512) @ Wc(512x768), bf16 MFMA.
// 128x128 tile, BK=64, global_load_lds width=16 into swizzled [128][64].
// ---------------------------------------------------------------------------
__global__ __launch_bounds__(256, 3) void matmul_fast(
    const unsigned short* __restrict__ Qb, const unsigned short* __restrict__ WcT,
    float* __restrict__ out) {
    const int mTile = blockIdx.x;  // 0..255
    const int nTile = blockIdx.y;  // 0..5
    const int t = threadIdx.x;
    const int wave = t >> 6, lane = t & 63;
    const int wm = wave >> 1, wn = wave & 1;
    const int quad = lane >> 4, l15 = lane & 15;
    __shared__ __align__(16) unsigned short As[128 * 64];
    __shared__ __align__(16) unsigned short Bs[128 * 64];
    const int b = mTile >> 5;
    const int s0 = (mTile & 31) * 128;
    const int nBase = nTile * 128;
    const int rl8 = lane >> 3, g = lane & 7;
    const int gs = g ^ rl8;                    // swizzled source granule
    f32x4_t acc[4][4] = {};

    for (int h = 0; h < 8; ++h) {
        const unsigned short* Qbh = Qb + (size_t)(b * H_ + h) * S_ * D_;
        #pragma unroll
        for (int k = 0; k < 4; ++k) {
            int ch = wave * 4 + k;             // chunk 0..15 (8 rows each)
            int row = ch * 8 + rl8;
            int s = s0 + row;
            int sc = (s > 0) ? (s - 1) : 0;
            async_copy16(Qbh + (size_t)sc * 64 + gs * 8, &As[ch * 512 + lane * 8]);
            async_copy16(WcT + (size_t)(nBase + row) * 512 + h * 64 + gs * 8,
                         &Bs[ch * 512 + lane * 8]);
        }
        __syncthreads();
        if (s0 == 0) {                          // block-uniform: zero A row 0 (s-1 = -1)
            if (t < 8) ((uint4*)As)[t] = make_uint4(0, 0, 0, 0);
            __syncthreads();
        }
        #pragma unroll
        for (int c = 0; c < 2; ++c) {
            int gk = c * 4 + quad;
            bfrag_t af[4], bf[4];
            #pragma unroll
            for (int i = 0; i < 4; ++i) {
                int row = wm * 64 + i * 16 + l15;
                af[i] = *(const bfrag_t*)&As[row * 64 + ((gk ^ (row & 7)) << 3)];
            }
            #pragma unroll
            for (int j = 0; j < 4; ++j) {
                int row = wn * 64 + j * 16 + l15;
                bf[j] = *(const bfrag_t*)&Bs[row * 64 + ((gk ^ (row & 7)) << 3)];
            }
            #pragma unroll
            for (int i = 0; i < 4; ++i)
                #pragma unroll
                for (int j = 0; j < 4; ++j)
                    acc[i][j] = MFMA16(af[i], bf[j], acc[i][j]);
        }
        __syncthreads();
    }
    const size_t mBase = (size_t)mTile * 128;
    #pragma unroll
    for (int i = 0; i < 4; ++i) {
        int mrow = wm * 64 + i * 16 + quad * 4;
        #pragma unroll
        for (int j = 0; j < 4; ++j) {
            int n = nBase + wn * 64 + j * 16 + l15;
            #pragma unroll
            for (int r = 0; r < 4; ++r)
                out[(mBase + mrow + r) * DM_ + n] = acc[i][j][r];
        }
    }
}

// Fallback GEMM reading fp32 Q (used only if ws can't hold Qbf).
__global__ __launch_bounds__(256, 2) void matmul_f32(
    const float* __restrict__ Qf, const unsigned short* __restrict__ WcT,
    float* __restrict__ out) {
    const int mTile = blockIdx.x, nTile = blockIdx.y;
    const int t = threadIdx.x;
    const int wave = t >> 6, lane = t & 63;
    const int wm = wave >> 1, wn = wave & 1;
    const int quad = lane >> 4, l15 = lane & 15;
    __shared__ __align__(16) unsigned short As[128][72];
    __shared__ __align__(16) unsigned short Bs[128][72];
    const int b = mTile >> 5;
    const int s0 = (mTile & 31) * 128;
    const int nBase = nTile * 128;
    f32x4_t acc[4][4] = {};
    for (int h = 0; h < 8; ++h) {
        const float* Qbh = Qf + (size_t)(b * H_ + h) * S_ * D_;
        #pragma unroll
        for (int i = 0; i < 8; ++i) {
            int f = i * 256 + t;
            int row = f >> 4, c4 = f & 15;
            int s = s0 + row;
            float4 q4 = make_float4(0.f, 0.f, 0.f, 0.f);
            if (s > 0) q4 = *(const float4*)(Qbh + (size_t)(s - 1) * D_ + c4 * 4);
            ushort4 u;
            u.x = f2bf(q4.x); u.y = f2bf(q4.y); u.z = f2bf(q4.z); u.w = f2bf(q4.w);
            *(ushort4*)(&As[row][c4 * 4]) = u;
        }
        #pragma unroll
        for (int i = 0; i < 4; ++i) {
            int f = i * 256 + t;
            int row = f >> 3, c8 = f & 7;
            uint4 w = *(const uint4*)(WcT + (size_t)(nBase + row) * 512 + h * 64 + c8 * 8);
            *(uint4*)(&Bs[row][c8 * 8]) = w;
        }
        __syncthreads();
        #pragma unroll
        for (int c = 0; c < 2; ++c) {
            int k0 = c * 32 + quad * 8;
            bfrag_t af[4], bf[4];
            #pragma unroll
            for (int i = 0; i < 4; ++i)
                af[i] = *(const bfrag_t*)(&As[wm * 64 + i * 16 + l15][k0]);
            #pragma unroll
            for (int j = 0; j < 4; ++j)
                bf[j] = *(const bfrag_t*)(&Bs[wn * 64 + j * 16 + l15][k0]);
            #pragma unroll
            for (int i = 0; i < 4; ++i)
                #pragma unroll
                for (int j = 0; j < 4; ++j)
                    acc[i][j] = MFMA16(af[i], bf[j], acc[i][j]);
        }
        __syncthreads();
    }
    const size_t mBase = (size_t)mTile * 128;
    #pragma unroll
    for (int i = 0; i < 4; ++i) {
        int mrow = wm * 64 + i * 16 + quad * 4;
        #pragma unroll
        for (int j = 0; j < 4; ++j) {
            int n = nBase + wn * 64 + j * 16 + l15;
            #pragma unroll
            for (int r = 0; r < 4; ++r)
                out[(mBase + mrow + r) * DM_ + n] = acc[i][j][r];
        }
    }
}

// ---------------------------------------------------------------------------
extern "C" void kernel_launch(void* const* d_in, const int* in_sizes, int n_in,
                              void* d_out, int out_size, void* d_ws, size_t ws_size,
                              hipStream_t stream) {
    const float* Q     = (const float*)d_in[0];
    const float* V     = (const float*)d_in[1];
    const float* trace = (const float*)d_in[2];
    const float* Wout  = (const float*)d_in[3];
    float* out = (float*)d_out;

    // ws layout
    float* gG   = (float*)d_ws;                                      // @0       128 KB
    float* gU   = gG + 32768;                                        // @128K    128 KB
    float* Tnew = gU + 32768;                                        // @256K    128 KB (unused hole)
    unsigned short* WcT = (unsigned short*)(Tnew + 32768);           // @384K    768 KB
    unsigned short* Qbf = WcT + 393216;                              // @1152K   32 MB
    float* gP = (float*)(Qbf + (size_t)B_ * H_ * S_ * D_);           // @33.1M   32 MB

    const size_t needQbf  = 1179648u + 33554432u;
    const size_t needFull = needQbf + 33554432u;
    const int mode = (ws_size >= needFull) ? 2 : ((ws_size >= needQbf) ? 1 : 0);

    if (mode == 2) {
        gram_kernel<true><<<dim3(16, 8, 8), 256, 0, stream>>>(Q, V, gG, gU, Qbf, gP, 1);
        reduce_kernel<<<dim3(8, 32), 256, 0, stream>>>(gP, gG, gU);
    } else {
        hipMemsetAsync(d_ws, 0, 2 * 32768 * sizeof(float), stream);
        gram_kernel<false><<<dim3(8, 8, 8), 256, 0, stream>>>(Q, V, gG, gU, Qbf, gP, mode >= 1);
    }
    wc_kernel<<<dim3(6, 8), 256, 0, stream>>>(gG, gU, trace, Wout, WcT);
    if (mode >= 1)
        matmul_fast<<<dim3(256, 6), 256, 0, stream>>>(Qbf, WcT, out);
    else
        matmul_f32<<<dim3(256, 6), 256, 0, stream>>>(Q, WcT, out);
}